// Round 1
// baseline (339.809 us; speedup 1.0000x reference)
//
#include <hip/hip_runtime.h>
#include <stdint.h>

// Problem constants
#define BB 4
#define TT 2048
#define CC 1024
#define HH 16
#define DH 64
#define NQKV 3072

typedef __bf16 bf16_t;
typedef __attribute__((ext_vector_type(8))) __bf16 bf16x8;
typedef __attribute__((ext_vector_type(4))) float f32x4;

#define MFMA16(a, b, c) __builtin_amdgcn_mfma_f32_16x16x32_bf16((a), (b), (c), 0, 0, 0)

// async global->LDS, 16B per lane. LDS dest = wave-uniform base + lane*16
// (passing per-thread base+lane*16 pointers is equivalent and R-verified).
__device__ __forceinline__ void gll16(const void* g, void* l) {
  typedef const __attribute__((address_space(1))) void* gp_t;
  typedef __attribute__((address_space(3))) void* lp_t;
  __builtin_amdgcn_global_load_lds((gp_t)(uintptr_t)g, (lp_t)(uintptr_t)l, 16, 0, 0);
}

// ---------------------------------------------------------------------------
// fp32 -> bf16 convert, 8 elems/thread (n multiple of 2048)
// ---------------------------------------------------------------------------
__global__ __launch_bounds__(256) void cvt_k(const float* __restrict__ src,
                                             bf16_t* __restrict__ dst, int n) {
  const int i8 = (blockIdx.x * 256 + threadIdx.x) * 8;
  if (i8 < n) {
    const f32x4 a = *(const f32x4*)(src + i8);
    const f32x4 b = *(const f32x4*)(src + i8 + 4);
    bf16x8 r;
    r[0] = (bf16_t)a[0]; r[1] = (bf16_t)a[1]; r[2] = (bf16_t)a[2]; r[3] = (bf16_t)a[3];
    r[4] = (bf16_t)b[0]; r[5] = (bf16_t)b[1]; r[6] = (bf16_t)b[2]; r[7] = (bf16_t)b[3];
    *(bf16x8*)(dst + i8) = r;
  }
}

// ---------------------------------------------------------------------------
// GEMM (bf16 A, bf16 W): C[m][n] = sum_k A[m][k]*W[n][k] (+bias[n]); K=1024.
// 256x256 tile, BK=64, 8 waves (2M x 4N), 128KiB LDS double-buffer.
// Distance-2 gll16 pipeline with counted vmcnt(8) across raw s_barriers:
//   tile t+2's 8 loads/thread are issued mid-tile-t into buf[t&1], which is
//   dead once all waves pulled both k-half fragment sets into registers
//   (lgkmcnt(0) + s_barrier). Boundary into tile t: vmcnt(8) leaves tile
//   t+1's 8 loads in flight (T3+T4). No __syncthreads in the loop (it would
//   emit vmcnt(0) and drain the pipeline).
// LDS swizzle: logical (row r, 16B-chunk q) at slot r*8 + (q ^ (r&7));
// the gather permutes the per-lane GLOBAL source so the linear DMA placement
// lands swizzled (both-sides-or-neither). ds_read_b128 then <=2-way banked.
// EPI==0: qkv epilogue (RoPE Q/K, 0.125*log2e folded into Q, scatter B,H,T,dh)
// EPI==1: bias epilogue into fp32 out0
// ---------------------------------------------------------------------------
template <int EPI>
__global__ __launch_bounds__(512, 2) void gemm_k(
    const bf16_t* __restrict__ A, const bf16_t* __restrict__ W,
    const float* __restrict__ bias,
    const float* __restrict__ fcos, const float* __restrict__ fsin,
    void* __restrict__ out0v, bf16_t* __restrict__ out1,
    bf16_t* __restrict__ out2) {
  __shared__ bf16_t Al[2][16384];  // [buf][256 rows * 64 k] (swizzled chunks)
  __shared__ bf16_t Bl[2][16384];
  const int K = 1024;
  const int tid = threadIdx.x;
  const int lane = tid & 63, wave = tid >> 6;
  const int quad = lane >> 4, c = lane & 15;
  const int wm = wave >> 2, wn = wave & 3;  // 2M x 4N wave grid
  const int mbase = blockIdx.y * 256, nbase = blockIdx.x * 256;

  f32x4 acc[8][4];
#pragma unroll
  for (int i = 0; i < 8; ++i)
#pragma unroll
    for (int j = 0; j < 4; ++j) acc[i][j] = (f32x4){0.f, 0.f, 0.f, 0.f};

  // permuted gather invariants: slot s holds logical (r=s>>3, q=(s&7)^(r&7)).
  // thread covers slots tid, tid+512, tid+1024, tid+1536 -> rows r0+{0,64,128,192},
  // all at chunk cc0 (since (r0+64k)&7 == r0&7).
  const int r0 = tid >> 3;
  const int cc0 = (tid & 7) ^ (r0 & 7);
  const bf16_t* Ag = A + (size_t)(mbase + r0) * K + cc0 * 8;
  const bf16_t* Bg = W + (size_t)(nbase + r0) * K + cc0 * 8;
  const int ls0 = tid * 8, ls1 = ls0 + 4096, ls2 = ls0 + 8192, ls3 = ls0 + 12288;

  // fragment-read invariants: element off = row*64 + ((chunk ^ (row&7)))*8,
  // row&7 == c&7 for all fragment rows. kh=1 flips chunk bit2 -> off ^ 32.
  const int rbA = (wm * 128 + c) * 64;
  const int rbB = (wn * 64 + c) * 64;
  const int sw0 = (quad ^ (c & 7)) * 8;

#define STAGE(CUR, T)                                  \
  {                                                    \
    const int ko_ = (T)*64;                            \
    gll16(Ag + ko_, &Al[CUR][ls0]);                    \
    gll16(Ag + 64 * K + ko_, &Al[CUR][ls1]);           \
    gll16(Ag + 128 * K + ko_, &Al[CUR][ls2]);          \
    gll16(Ag + 192 * K + ko_, &Al[CUR][ls3]);          \
    gll16(Bg + ko_, &Bl[CUR][ls0]);                    \
    gll16(Bg + 64 * K + ko_, &Bl[CUR][ls1]);           \
    gll16(Bg + 128 * K + ko_, &Bl[CUR][ls2]);          \
    gll16(Bg + 192 * K + ko_, &Bl[CUR][ls3]);          \
  }

// One K-tile. VM is the literal vmcnt immediate at the boundary (8 = next
// tile's loads stay in flight; 0 only on the last tile). DOSTAGE: issue tile
// T+2 into buf[CUR] after the post-read barrier.
#define KTILE(T, CUR, VM, DOSTAGE)                                            \
  {                                                                           \
    asm volatile("s_waitcnt vmcnt(" #VM ")" ::: "memory");                    \
    __builtin_amdgcn_s_barrier();                                             \
    asm volatile("" ::: "memory");                                            \
    bf16x8 af0[8], bf0[4], af1[8], bf1[4];                                    \
    _Pragma("unroll") for (int mi = 0; mi < 8; ++mi)                          \
        af0[mi] = *(const bf16x8*)&Al[CUR][rbA + mi * 1024 + sw0];            \
    _Pragma("unroll") for (int ni = 0; ni < 4; ++ni)                          \
        bf0[ni] = *(const bf16x8*)&Bl[CUR][rbB + ni * 1024 + sw0];            \
    __builtin_amdgcn_s_setprio(1);                                            \
    _Pragma("unroll") for (int mi = 0; mi < 8; ++mi)                          \
        _Pragma("unroll") for (int ni = 0; ni < 4; ++ni)                      \
            acc[mi][ni] = MFMA16(af0[mi], bf0[ni], acc[mi][ni]);              \
    __builtin_amdgcn_s_setprio(0);                                            \
    _Pragma("unroll") for (int mi = 0; mi < 8; ++mi)                          \
        af1[mi] = *(const bf16x8*)&Al[CUR][rbA + mi * 1024 + (sw0 ^ 32)];     \
    _Pragma("unroll") for (int ni = 0; ni < 4; ++ni)                          \
        bf1[ni] = *(const bf16x8*)&Bl[CUR][rbB + ni * 1024 + (sw0 ^ 32)];     \
    asm volatile("s_waitcnt lgkmcnt(0)" ::: "memory");                        \
    __builtin_amdgcn_s_barrier(); /* buf[CUR] fully consumed by all waves */  \
    asm volatile("" ::: "memory");                                            \
    if (DOSTAGE) STAGE(CUR, (T) + 2);                                         \
    __builtin_amdgcn_s_setprio(1);                                            \
    _Pragma("unroll") for (int mi = 0; mi < 8; ++mi)                          \
        _Pragma("unroll") for (int ni = 0; ni < 4; ++ni)                      \
            acc[mi][ni] = MFMA16(af1[mi], bf1[ni], acc[mi][ni]);              \
    __builtin_amdgcn_s_setprio(0);                                            \
  }

  // prologue: tiles 0 and 1 in flight (16 loads/thread)
  STAGE(0, 0);
  STAGE(1, 1);

  // tiles 0..13: steady state (stage t+2, boundary keeps 8 loads in flight)
  for (int fj = 0; fj < 7; ++fj) {
    const int t0 = 2 * fj;
    KTILE(t0, 0, 8, 1)
    KTILE(t0 + 1, 1, 8, 1)
  }
  // tail: tile 14 (15's loads still in flight), tile 15 (full drain)
  KTILE(14, 0, 8, 0)
  KTILE(15, 1, 0, 0)
#undef KTILE
#undef STAGE

  // epilogue. C/D layout: col = lane&15 (+16*ni), row = quad*4 + r (+16*mi)
  const float qscale = 0.18033688011112042f;  // 0.125 * log2(e)
#pragma unroll
  for (int mi = 0; mi < 8; ++mi) {
#pragma unroll
    for (int ni = 0; ni < 4; ++ni) {
      const int n = nbase + wn * 64 + ni * 16 + c;
      const float bv = bias[n];
#pragma unroll
      for (int r = 0; r < 4; ++r) {
        const int m = mbase + wm * 128 + mi * 16 + quad * 4 + r;
        float v = acc[mi][ni][r] + bv;
        if (EPI == 0) {
          bf16_t* out0 = (bf16_t*)out0v;
          const int sel = n >> 10;  // 0=q 1=k 2=v
          const int nl = n & 1023;
          const int h = nl >> 6, d = nl & 63;
          const int b = m >> 11, t = m & 2047;
          const int dst = ((b * HH + h) * TT + t) * DH + d;
          if (sel < 2) {
            const float pv = __shfl_xor(v, 1, 64);  // RoPE partner (col n^1)
            const int d2 = d >> 1;
            const float cs = fcos[t * 32 + d2];
            const float sn = fsin[t * 32 + d2];
            float o = ((d & 1) == 0) ? (v * cs - pv * sn) : (pv * sn + v * cs);
            if (sel == 0) {
              o *= qscale;
              out0[dst] = (bf16_t)o;
            } else {
              out1[dst] = (bf16_t)o;
            }
          } else {
            out2[dst] = (bf16_t)v;
          }
        } else {
          float* outf = (float*)out0v;
          outf[(size_t)m * CC + n] = v;
        }
      }
    }
  }
}

// ---------------------------------------------------------------------------
// Flash attention, causal. Q pre-scaled by 0.125*log2(e) (exp2 domain).
// R8-verified version (REVERT of R9's global-K experiment: MFMA operands must
// come from a buffer filled >=1 iteration ahead; direct global K reads put
// ~200-900cyc load latency on the critical path -> 105->174us regression).
// Uniform-work causal pairing: exactly 33 kv-iterations per block; kv-loop
// unrolled x2 (compile-time LDS buffer index); rowsum via MFMA vs ones;
// XOR-swizzled LDS (0 bank conflicts).
// ---------------------------------------------------------------------------
__global__ __launch_bounds__(256, 4) void attn_k(const bf16_t* __restrict__ Q,
                                                 const bf16_t* __restrict__ Kv,
                                                 const bf16_t* __restrict__ V,
                                                 bf16_t* __restrict__ O) {
  __shared__ bf16_t KS[2][64 * 64];
  __shared__ bf16_t VtS[2][64 * 64];
  __shared__ bf16_t PS[4][16 * 64];

  const int tid = threadIdx.x;
  const int lane = tid & 63, wave = tid >> 6;
  const int quad = lane >> 4, c = lane & 15;
  const int bi = blockIdx.x;
  const int pair = bi & 15, h = (bi >> 4) & 15, b = bi >> 8;
  const int qtA = pair, qtB = 31 - pair;
  const int nA = qtA + 1;  // kv tiles in phase A

  const bf16_t* Qh = Q + ((b * HH + h) * TT) * DH;
  const bf16_t* Kh = Kv + ((b * HH + h) * TT) * DH;
  const bf16_t* Vh = V + ((b * HH + h) * TT) * DH;

  const f32x4 zero4 = {0.f, 0.f, 0.f, 0.f};
  bf16x8 ones8;
#pragma unroll
  for (int i = 0; i < 8; ++i) ones8[i] = (bf16_t)1.0f;

  // staging bases (per-thread, loop-invariant)
  const int krow0 = tid >> 3, kc8 = tid & 7, krow1 = krow0 + 32;
  const bf16_t* kbase0 = Kh + krow0 * DH + kc8 * 8;
  const bf16_t* kbase1 = Kh + krow1 * DH + kc8 * 8;
  const int vsb = tid >> 2, vjp = tid & 3;
  const int vrg = vsb & 7, vc8 = vsb >> 3;
  const int vd0 = vc8 * 8 + vjp * 2, vd1 = vd0 + 1;
  const bf16_t* vbase = Vh + vrg * 8 * DH + vd0;

  // invariant swizzled fragment offsets (elements): row c, chunk (quad|quad+4)
  const int sw = c & 7;
  const int e0 = c * 64 + (quad ^ sw) * 8;
  const int e1 = c * 64 + ((quad + 4) ^ sw) * 8;

  bf16x8 kr0, kr1;
  uint32_t vr[8];
  auto load_tile = [&](int eoff) {
    kr0 = *(const bf16x8*)(kbase0 + eoff);
    kr1 = *(const bf16x8*)(kbase1 + eoff);
    const bf16_t* vp = vbase + eoff;
#pragma unroll
    for (int i = 0; i < 8; ++i) vr[i] = *(const uint32_t*)(vp + i * DH);
  };
  auto store_tile = [&](int buf) {
    *(bf16x8*)&KS[buf][(krow0 * 8 + (kc8 ^ (krow0 & 7))) * 8] = kr0;
    *(bf16x8*)&KS[buf][(krow1 * 8 + (kc8 ^ (krow1 & 7))) * 8] = kr1;
    union { bf16x8 v; uint16_t u[8]; } colA, colB;
#pragma unroll
    for (int i = 0; i < 8; ++i) {
      colA.u[i] = (uint16_t)(vr[i] & 0xffffu);
      colB.u[i] = (uint16_t)(vr[i] >> 16);
    }
    *(bf16x8*)&VtS[buf][(vd0 * 8 + (vrg ^ (vd0 & 7))) * 8] = colA.v;
    *(bf16x8*)&VtS[buf][(vd1 * 8 + (vrg ^ (vd1 & 7))) * 8] = colB.v;
  };

  // phase state (A first)
  int qtbase = qtA * 64;
  bf16x8 qf0 = *(const bf16x8*)(Qh + (qtbase + wave * 16 + c) * DH + quad * 8);
  bf16x8 qf1 = *(const bf16x8*)(Qh + (qtbase + wave * 16 + c) * DH + 32 + quad * 8);

  f32x4 o_acc[4] = {zero4, zero4, zero4, zero4};
  float m_r[4] = {-1e30f, -1e30f, -1e30f, -1e30f};
  float l_r[4] = {0.f, 0.f, 0.f, 0.f};

  auto write_O = [&](int qtb) {
#pragma unroll
    for (int r = 0; r < 4; ++r) {
      const int qg = qtb + wave * 16 + quad * 4 + r;
      const float inv = 1.0f / l_r[r];
#pragma unroll
      for (int ni = 0; ni < 4; ++ni)
        O[(b * TT + qg) * CC + h * 64 + ni * 16 + c] =
            (bf16_t)(o_acc[ni][r] * inv);
    }
  };

  load_tile(0);
  store_tile(0);
  __syncthreads();
  int coff = 0;   // current tile element offset into K/V
  int kkey = 0;   // current tile key-index base

// one kv iteration; CUR is a literal 0/1 -> LDS addresses fold to constants
#define ATTN_ITER(FI, CUR)                                                     \
  {                                                                            \
    const int fi_ = (FI);                                                      \
    const bool pre_ = fi_ < 32;                                                \
    const int noff_ = (fi_ + 1 == nA) ? 0 : coff + 64 * DH;                    \
    if (pre_) load_tile(noff_);                                                \
    bf16x8 kf0[4], kf1[4];                                                     \
    _Pragma("unroll") for (int ni = 0; ni < 4; ++ni) {                         \
      kf0[ni] = *(const bf16x8*)&KS[CUR][ni * 1024 + e0];                      \
      kf1[ni] = *(const bf16x8*)&KS[CUR][ni * 1024 + e1];                      \
    }                                                                          \
    f32x4 s[4];                                                                \
    _Pragma("unroll") for (int ni = 0; ni < 4; ++ni) {                         \
      f32x4 t = MFMA16(qf0, kf0[ni], zero4);                                   \
      t = MFMA16(qf1, kf1[ni], t);                                             \
      s[ni] = t;                                                               \
    }                                                                          \
    const int minq_ = qtbase + wave * 16;                                      \
    if (kkey + 63 > minq_) {                                                   \
      _Pragma("unroll") for (int ni = 0; ni < 4; ++ni)                         \
          _Pragma("unroll") for (int r = 0; r < 4; ++r) {                      \
        const int key_ = kkey + ni * 16 + c;                                   \
        const int qg_ = minq_ + quad * 4 + r;                                  \
        if (key_ > qg_) s[ni][r] = -1e30f;                                     \
      }                                                                        \
    }                                                                          \
    float alpha[4];                                                            \
    _Pragma("unroll") for (int r = 0; r < 4; ++r) {                            \
      float mx = fmaxf(fmaxf(s[0][r], s[1][r]), fmaxf(s[2][r], s[3][r]));      \
      mx = fmaxf(mx, __shfl_xor(mx, 1, 64));                                   \
      mx = fmaxf(mx, __shfl_xor(mx, 2, 64));                                   \
      mx = fmaxf(mx, __shfl_xor(mx, 4, 64));                                   \
      mx = fmaxf(mx, __shfl_xor(mx, 8, 64));                                   \
      const float mnew = fmaxf(m_r[r], mx);                                    \
      alpha[r] = __builtin_amdgcn_exp2f(m_r[r] - mnew);                        \
      m_r[r] = mnew;                                                           \
    }                                                                          \
    _Pragma("unroll") for (int ni = 0; ni < 4; ++ni)                           \
        _Pragma("unroll") for (int r = 0; r < 4; ++r) {                        \
      const float p = __builtin_amdgcn_exp2f(s[ni][r] - m_r[r]);               \
      const int prow_ = quad * 4 + r, pcol_ = ni * 16 + c;                     \
      PS[wave][(prow_ * 8 + ((pcol_ >> 3) ^ (prow_ & 7))) * 8 + (pcol_ & 7)] = \
          (bf16_t)p;                                                           \
    }                                                                          \
    _Pragma("unroll") for (int r = 0; r < 4; ++r) {                            \
      _Pragma("unroll") for (int ni = 0; ni < 4; ++ni)                         \
          o_acc[ni][r] *= alpha[r];                                            \
    }                                                                          \
    asm volatile("s_waitcnt lgkmcnt(0)" ::: "memory");                         \
    const bf16x8 p0 = *(const bf16x8*)&PS[wave][e0];                           \
    const bf16x8 p1 = *(const bf16x8*)&PS[wave][e1];                           \
    f32x4 rs = MFMA16(p0, ones8, zero4);                                       \
    rs = MFMA16(p1, ones8, rs);                                                \
    _Pragma("unroll") for (int ni = 0; ni < 4; ++ni) {                         \
      const bf16x8 v0 = *(const bf16x8*)&VtS[CUR][ni * 1024 + e0];             \
      const bf16x8 v1 = *(const bf16x8*)&VtS[CUR][ni * 1024 + e1];             \
      o_acc[ni] = MFMA16(p0, v0, o_acc[ni]);                                   \
      o_acc[ni] = MFMA16(p1, v1, o_acc[ni]);                                   \
    }                                                                          \
    _Pragma("unroll") for (int r = 0; r < 4; ++r)                              \
        l_r[r] = l_r[r] * alpha[r] + rs[r];                                    \
    if (fi_ == nA - 1) {                                                       \
      write_O(qtbase);                                                         \
      qtbase = qtB * 64;                                                       \
      qf0 = *(const bf16x8*)(Qh + (qtbase + wave * 16 + c) * DH + quad * 8);   \
      qf1 = *(const bf16x8*)(Qh + (qtbase + wave * 16 + c) * DH + 32 +         \
                             quad * 8);                                        \
      _Pragma("unroll") for (int r = 0; r < 4; ++r) {                          \
        m_r[r] = -1e30f;                                                       \
        l_r[r] = 0.f;                                                          \
      }                                                                        \
      _Pragma("unroll") for (int ni = 0; ni < 4; ++ni) o_acc[ni] = zero4;      \
    }                                                                          \
    if (pre_) store_tile(1 - (CUR));                                           \
    __syncthreads();                                                           \
    coff = noff_;                                                              \
    kkey = (fi_ + 1 == nA) ? 0 : kkey + 64;                                    \
  }

  for (int fj = 0; fj < 16; ++fj) {
    ATTN_ITER(2 * fj, 0)
    ATTN_ITER(2 * fj + 1, 1)
  }
  ATTN_ITER(32, 0)
#undef ATTN_ITER

  write_O(qtbase);  // phase B epilogue
}

// ---------------------------------------------------------------------------
extern "C" void kernel_launch(void* const* d_in, const int* in_sizes, int n_in,
                              void* d_out, int out_size, void* d_ws,
                              size_t ws_size, hipStream_t stream) {
  // Resolve inputs by unique element-count signature.
  const float *x = nullptr, *fcos = nullptr, *fsin = nullptr;
  const float *qkv_w = nullptr, *qkv_b = nullptr, *proj_w = nullptr, *proj_b = nullptr;
  for (int i = 0; i < n_in; ++i) {
    const int s = in_sizes[i];
    const float* p = (const float*)d_in[i];
    if (s == BB * TT * CC) x = p;                        // 8388608
    else if (s == TT * (DH / 2)) { if (!fcos) fcos = p; else fsin = p; }
    else if (s == NQKV * CC) qkv_w = p;                  // 3145728
    else if (s == NQKV) qkv_b = p;                       // 3072
    else if (s == CC * CC) proj_w = p;                   // 1048576
    else if (s == CC) proj_b = p;                        // 1024
    // mask (TT*TT) unused; causality is structural
  }

  const size_t NE = (size_t)BB * TT * CC;  // 8388608
  bf16_t* Qb = (bf16_t*)d_ws;
  bf16_t* Kb = Qb + NE;
  bf16_t* Vb = Kb + NE;
  bf16_t* Ob = Vb + NE;
  // dead-region reuse (all hazard-free under stream ordering):
  bf16_t* xb = Ob;                 // x_bf16 lives in Ob region until attn
  bf16_t* wqkvb = (bf16_t*)d_out;  // qkv_w bf16 in d_out until gemm3 writes it
  bf16_t* wpb = Qb;                // proj_w bf16 in Qb region (dead after attn)

  // converts
  cvt_k<<<dim3((int)(NE / 2048)), 256, 0, stream>>>(x, xb, (int)NE);
  cvt_k<<<dim3(NQKV * CC / 2048), 256, 0, stream>>>(qkv_w, wqkvb, NQKV * CC);

  // 1) qkv = x @ qkv_w^T + b, fused RoPE + head-split (+0.125*log2e into Q)
  gemm_k<0><<<dim3(NQKV / 256, (BB * TT) / 256), 512, 0, stream>>>(
      xb, wqkvb, qkv_b, fcos, fsin, (void*)Qb, Kb, Vb);
  // 2) causal flash attention -> Ob (B*T, C) bf16 (overwrites xb)
  attn_k<<<dim3(BB * HH * 16), 256, 0, stream>>>(Qb, Kb, Vb, Ob);
  // 3) convert proj_w (Qb dead now), then out = Ob @ proj_w^T + proj_b (fp32)
  cvt_k<<<dim3(CC * CC / 2048), 256, 0, stream>>>(proj_w, wpb, CC * CC);
  gemm_k<1><<<dim3(CC / 256, (BB * TT) / 256), 512, 0, stream>>>(
      Ob, wpb, proj_b, nullptr, nullptr, d_out, nullptr, nullptr);
}

// Round 2
// 335.052 us; speedup vs baseline: 1.0142x; 1.0142x over previous
//
#include <hip/hip_runtime.h>
#include <stdint.h>

// Problem constants
#define BB 4
#define TT 2048
#define CC 1024
#define HH 16
#define DH 64
#define NQKV 3072

typedef __bf16 bf16_t;
typedef __attribute__((ext_vector_type(8))) __bf16 bf16x8;
typedef __attribute__((ext_vector_type(4))) float f32x4;

#define MFMA16(a, b, c) __builtin_amdgcn_mfma_f32_16x16x32_bf16((a), (b), (c), 0, 0, 0)

// async global->LDS, 16B per lane. LDS dest = wave-uniform base + lane*16.
__device__ __forceinline__ void gll16(const void* g, void* l) {
  typedef const __attribute__((address_space(1))) void* gp_t;
  typedef __attribute__((address_space(3))) void* lp_t;
  __builtin_amdgcn_global_load_lds((gp_t)(uintptr_t)g, (lp_t)(uintptr_t)l, 16, 0, 0);
}

template <int N>
__device__ __forceinline__ void vmwait() {
  if constexpr (N == 0) asm volatile("s_waitcnt vmcnt(0)" ::: "memory");
  else if constexpr (N == 2) asm volatile("s_waitcnt vmcnt(2)" ::: "memory");
  else if constexpr (N == 6) asm volatile("s_waitcnt vmcnt(6)" ::: "memory");
  else if constexpr (N == 8) asm volatile("s_waitcnt vmcnt(8)" ::: "memory");
}

#define LGKM0                                          \
  do {                                                 \
    asm volatile("s_waitcnt lgkmcnt(0)" ::: "memory"); \
    __builtin_amdgcn_sched_barrier(0);                 \
  } while (0)
#define BAR() __builtin_amdgcn_s_barrier()

// ---------------------------------------------------------------------------
// fp32 -> bf16 convert, 8 elems/thread (n multiple of 2048)
// ---------------------------------------------------------------------------
__global__ __launch_bounds__(256) void cvt_k(const float* __restrict__ src,
                                             bf16_t* __restrict__ dst, int n) {
  const int i8 = (blockIdx.x * 256 + threadIdx.x) * 8;
  if (i8 < n) {
    const f32x4 a = *(const f32x4*)(src + i8);
    const f32x4 b = *(const f32x4*)(src + i8 + 4);
    bf16x8 r;
    r[0] = (bf16_t)a[0]; r[1] = (bf16_t)a[1]; r[2] = (bf16_t)a[2]; r[3] = (bf16_t)a[3];
    r[4] = (bf16_t)b[0]; r[5] = (bf16_t)b[1]; r[6] = (bf16_t)b[2]; r[7] = (bf16_t)b[3];
    *(bf16x8*)(dst + i8) = r;
  }
}

// ---------------------------------------------------------------------------
// GEMM (bf16 A, bf16 W): C[m][n] = sum_k A[m][k]*W[n][k] (+bias[n]); K=1024.
// 256 x (NI*64) tile, BK=64, 8 waves (2M x 4N), 4 fine phases per K-tile
// (m201-style): each phase = {ds_read one operand quadrant | issue one stage
// unit -> BAR -> lgkm0 -> setprio1 -> 4xNI MFMA -> setprio0 -> [vmwait] BAR}.
// Stage units match phase deadness so tile t+1/t+2 loads recycle regions of
// the live buffers:  A-unit u = per-wave m-half rows {u*64..u*64+63} (+128),
// B-unit kh = all rows, k-half kh.  Schedule per tile t:
//   P1(A0xBkh0): stage A1(t+1)   P2(A1xBkh0): stage Bkh0(t+2)
//   P3(A0xBkh1): -               P4(A1xBkh1): stage Bkh1(t+2), A0(t+2)
// Counted waits (verified load-by-load, incl. prologue/tail):
//   W1 = vmcnt(8|6) before P4's trailing BAR (protects next tile's P1/P3)
//   W2 = vmcnt(8|6) before P1's trailing BAR (protects P2/P4's A1 reads)
// Per-wave vmcnt + barrier => global visibility. Never drains in steady state.
// LDS XOR-swizzle (chunk ^= row bits) via permuted per-lane GLOBAL source so
// the linear DMA lands swizzled; ds_read_b128 conflict-free (checked per
// 8-lane bank sweep). EPI==0: RoPE/scatter epilogue; EPI==1: bias+fp32.
// ---------------------------------------------------------------------------
template <int EPI, int NI>
__global__ __launch_bounds__(512, 2) void gemm_k(
    const bf16_t* __restrict__ A, const bf16_t* __restrict__ W,
    const float* __restrict__ bias,
    const float* __restrict__ fcos, const float* __restrict__ fsin,
    void* __restrict__ out0v, bf16_t* __restrict__ out1,
    bf16_t* __restrict__ out2) {
  constexpr int BN = NI * 64;
  __shared__ bf16_t Al[2][2][8192];      // [buf][m-half unit][128 rows x 64 k]
  __shared__ bf16_t Bl[2][2][BN * 32];   // [buf][k-half unit][BN rows x 32 k]
  const int K = 1024;
  const int tid = threadIdx.x;
  const int wave = tid >> 6;
  const int quad = (tid & 63) >> 4, c = tid & 15;
  const int wm = wave >> 2, wn = wave & 3;  // 2M x 4N wave grid
  const int mbase = blockIdx.y * 256, nbase = blockIdx.x * BN;

  f32x4 acc[8][NI];
#pragma unroll
  for (int i = 0; i < 8; ++i)
#pragma unroll
    for (int j = 0; j < NI; ++j) acc[i][j] = (f32x4){0.f, 0.f, 0.f, 0.f};

  // fragment-read invariants.
  // A unit elem = r''*64 + ((kh*4+quad) ^ (r''&7))*8, r'' = wm*64+(mi&3)*16+c
  const int base_r = wm * 64 + c;
  const int swA0 = (quad ^ (c & 7)) * 8;  // kh1: swA0 ^ 32
  // B unit elem = r*32 + (quad ^ ((r>>1)&3))*8, r = wn*NI*16 + ni*16 + c
  const int rbB = (wn * (NI * 16) + c) * 32;
  const int swB = (quad ^ ((c >> 1) & 3)) * 8;

  // stage sources (inverse-swizzled per-lane global pointers; LDS lands linear)
  const int sr = tid >> 3;                               // A slot row 0..63
  const int saq = ((tid & 7) ^ (sr & 7)) * 8;            // A swizzled k-chunk
  const bf16_t* aS0 = A + (size_t)(mbase + sr) * K + saq;        // unit0 (+128 for 2nd)
  const bf16_t* aS1 = A + (size_t)(mbase + 64 + sr) * K + saq;   // unit1
  const int br = tid >> 2;                               // B slot row 0..127
  const int sbq = ((tid & 3) ^ ((tid >> 3) & 3)) * 8;
  const bf16_t* bS0 = W + (size_t)(nbase + br) * K + sbq;  // kh0
  const bf16_t* bS1 = bS0 + 32;                            // kh1

#define STAGE_A0(BUF, KT)                                                \
  {                                                                      \
    gll16(aS0 + (KT)*64, &Al[BUF][0][tid * 8]);                          \
    gll16(aS0 + 128 * K + (KT)*64, &Al[BUF][0][tid * 8 + 4096]);         \
  }
#define STAGE_A1(BUF, KT)                                                \
  {                                                                      \
    gll16(aS1 + (KT)*64, &Al[BUF][1][tid * 8]);                          \
    gll16(aS1 + 128 * K + (KT)*64, &Al[BUF][1][tid * 8 + 4096]);         \
  }
#define STAGE_B0(BUF, KT)                                                \
  {                                                                      \
    gll16(bS0 + (KT)*64, &Bl[BUF][0][tid * 8]);                          \
    if constexpr (NI == 4)                                               \
      gll16(bS0 + 128 * K + (KT)*64, &Bl[BUF][0][tid * 8 + 4096]);       \
  }
#define STAGE_B1(BUF, KT)                                                \
  {                                                                      \
    gll16(bS1 + (KT)*64, &Bl[BUF][1][tid * 8]);                          \
    if constexpr (NI == 4)                                               \
      gll16(bS1 + 128 * K + (KT)*64, &Bl[BUF][1][tid * 8 + 4096]);       \
  }

  constexpr int WS = (NI == 4) ? 8 : 6;  // steady-state counted wait

// One K-tile = 4 fine phases. W2/WN are vmcnt immediates (W2 guards next
// phases' A1 reads; WN guards next TILE's P1/P3 reads). S1/S2/S4 gate staging.
#define KTILE(BUF, W2, WN, S1, S2, S4, KT)                                    \
  {                                                                           \
    const int kt_ = (KT);                                                     \
    bf16x8 a_[4], b_[NI];                                                     \
    /* P1: A-unit0 x B-kh0 */                                                 \
    _Pragma("unroll") for (int i = 0; i < 4; ++i)                             \
        a_[i] = *(const bf16x8*)&Al[BUF][0][(base_r + i * 16) * 64 + swA0];   \
    _Pragma("unroll") for (int i = 0; i < NI; ++i)                            \
        b_[i] = *(const bf16x8*)&Bl[BUF][0][rbB + i * 512 + swB];             \
    if (S1) STAGE_A1((BUF) ^ 1, kt_ + 1);                                     \
    BAR();                                                                    \
    LGKM0;                                                                    \
    __builtin_amdgcn_s_setprio(1);                                            \
    _Pragma("unroll") for (int mi = 0; mi < 4; ++mi)                          \
        _Pragma("unroll") for (int ni = 0; ni < NI; ++ni)                     \
            acc[mi][ni] = MFMA16(a_[mi], b_[ni], acc[mi][ni]);                \
    __builtin_amdgcn_s_setprio(0);                                            \
    vmwait<W2>();                                                             \
    BAR();                                                                    \
    /* P2: A-unit1 x B-kh0 */                                                 \
    _Pragma("unroll") for (int i = 0; i < 4; ++i)                             \
        a_[i] = *(const bf16x8*)&Al[BUF][1][(base_r + i * 16) * 64 + swA0];   \
    if (S2) STAGE_B0(BUF, kt_ + 2);                                           \
    BAR();                                                                    \
    LGKM0;                                                                    \
    __builtin_amdgcn_s_setprio(1);                                            \
    _Pragma("unroll") for (int mi = 0; mi < 4; ++mi)                          \
        _Pragma("unroll") for (int ni = 0; ni < NI; ++ni)                     \
            acc[4 + mi][ni] = MFMA16(a_[mi], b_[ni], acc[4 + mi][ni]);        \
    __builtin_amdgcn_s_setprio(0);                                            \
    BAR();                                                                    \
    /* P3: A-unit0 x B-kh1 */                                                 \
    _Pragma("unroll") for (int i = 0; i < 4; ++i)                             \
        a_[i] = *(const bf16x8*)&Al[BUF][0]                                   \
                    [(base_r + i * 16) * 64 + (swA0 ^ 32)];                   \
    _Pragma("unroll") for (int i = 0; i < NI; ++i)                            \
        b_[i] = *(const bf16x8*)&Bl[BUF][1][rbB + i * 512 + swB];             \
    BAR();                                                                    \
    LGKM0;                                                                    \
    __builtin_amdgcn_s_setprio(1);                                            \
    _Pragma("unroll") for (int mi = 0; mi < 4; ++mi)                          \
        _Pragma("unroll") for (int ni = 0; ni < NI; ++ni)                     \
            acc[mi][ni] = MFMA16(a_[mi], b_[ni], acc[mi][ni]);                \
    __builtin_amdgcn_s_setprio(0);                                            \
    BAR();                                                                    \
    /* P4: A-unit1 x B-kh1 */                                                 \
    _Pragma("unroll") for (int i = 0; i < 4; ++i)                             \
        a_[i] = *(const bf16x8*)&Al[BUF][1]                                   \
                    [(base_r + i * 16) * 64 + (swA0 ^ 32)];                   \
    if (S4) { STAGE_B1(BUF, kt_ + 2); STAGE_A0(BUF, kt_ + 2); }               \
    BAR();                                                                    \
    LGKM0;                                                                    \
    __builtin_amdgcn_s_setprio(1);                                            \
    _Pragma("unroll") for (int mi = 0; mi < 4; ++mi)                          \
        _Pragma("unroll") for (int ni = 0; ni < NI; ++ni)                     \
            acc[4 + mi][ni] = MFMA16(a_[mi], b_[ni], acc[4 + mi][ni]);        \
    __builtin_amdgcn_s_setprio(0);                                            \
    vmwait<WN>();                                                             \
    BAR();                                                                    \
  }

  // prologue: tile 0 fully + tile 1 minus A1(1); then W1(0)+BAR.
  STAGE_B0(0, 0); STAGE_B1(0, 0); STAGE_A0(0, 0); STAGE_A1(0, 0);
  STAGE_B0(1, 1); STAGE_B1(1, 1); STAGE_A0(1, 1);
  vmwait<WS>();
  BAR();

  for (int fj = 0; fj < 7; ++fj) {
    const int t0 = 2 * fj;
    KTILE(0, WS, WS, 1, 1, 1, t0)
    KTILE(1, WS, WS, 1, 1, 1, t0 + 1)
  }
  KTILE(0, WS, 2, 1, 0, 0, 14)  // stages only A1(15); next-tile wait = 2
  KTILE(1, 0, 0, 0, 0, 0, 15)   // full drain of A1(15); no stages
#undef KTILE
#undef STAGE_A0
#undef STAGE_A1
#undef STAGE_B0
#undef STAGE_B1

  // epilogue. C/D layout: col = lane&15 (+16*ni), row = quad*4 + r (+16*mi)
  const float qscale = 0.18033688011112042f;  // 0.125 * log2(e)
#pragma unroll
  for (int mi = 0; mi < 8; ++mi) {
#pragma unroll
    for (int ni = 0; ni < NI; ++ni) {
      const int n = nbase + wn * (NI * 16) + ni * 16 + c;
      const float bv = bias[n];
#pragma unroll
      for (int r = 0; r < 4; ++r) {
        const int m = mbase + wm * 128 + mi * 16 + quad * 4 + r;
        float v = acc[mi][ni][r] + bv;
        if (EPI == 0) {
          bf16_t* out0 = (bf16_t*)out0v;
          const int sel = n >> 10;  // 0=q 1=k 2=v
          const int nl = n & 1023;
          const int h = nl >> 6, d = nl & 63;
          const int b = m >> 11, t = m & 2047;
          const int dst = ((b * HH + h) * TT + t) * DH + d;
          if (sel < 2) {
            const float pv = __shfl_xor(v, 1, 64);  // RoPE partner (col n^1)
            const int d2 = d >> 1;
            const float cs = fcos[t * 32 + d2];
            const float sn = fsin[t * 32 + d2];
            float o = ((d & 1) == 0) ? (v * cs - pv * sn) : (pv * sn + v * cs);
            if (sel == 0) {
              o *= qscale;
              out0[dst] = (bf16_t)o;
            } else {
              out1[dst] = (bf16_t)o;
            }
          } else {
            out2[dst] = (bf16_t)v;
          }
        } else {
          float* outf = (float*)out0v;
          outf[(size_t)m * CC + n] = v;
        }
      }
    }
  }
}

// ---------------------------------------------------------------------------
// Flash attention, causal. Q pre-scaled by 0.125*log2(e) (exp2 domain).
// R8-verified version (REVERT of R9's global-K experiment: MFMA operands must
// come from a buffer filled >=1 iteration ahead; direct global K reads put
// ~200-900cyc load latency on the critical path -> 105->174us regression).
// Uniform-work causal pairing: exactly 33 kv-iterations per block; kv-loop
// unrolled x2 (compile-time LDS buffer index); rowsum via MFMA vs ones;
// XOR-swizzled LDS (0 bank conflicts).
// ---------------------------------------------------------------------------
__global__ __launch_bounds__(256, 4) void attn_k(const bf16_t* __restrict__ Q,
                                                 const bf16_t* __restrict__ Kv,
                                                 const bf16_t* __restrict__ V,
                                                 bf16_t* __restrict__ O) {
  __shared__ bf16_t KS[2][64 * 64];
  __shared__ bf16_t VtS[2][64 * 64];
  __shared__ bf16_t PS[4][16 * 64];

  const int tid = threadIdx.x;
  const int lane = tid & 63, wave = tid >> 6;
  const int quad = lane >> 4, c = lane & 15;
  const int bi = blockIdx.x;
  const int pair = bi & 15, h = (bi >> 4) & 15, b = bi >> 8;
  const int qtA = pair, qtB = 31 - pair;
  const int nA = qtA + 1;  // kv tiles in phase A

  const bf16_t* Qh = Q + ((b * HH + h) * TT) * DH;
  const bf16_t* Kh = Kv + ((b * HH + h) * TT) * DH;
  const bf16_t* Vh = V + ((b * HH + h) * TT) * DH;

  const f32x4 zero4 = {0.f, 0.f, 0.f, 0.f};
  bf16x8 ones8;
#pragma unroll
  for (int i = 0; i < 8; ++i) ones8[i] = (bf16_t)1.0f;

  // staging bases (per-thread, loop-invariant)
  const int krow0 = tid >> 3, kc8 = tid & 7, krow1 = krow0 + 32;
  const bf16_t* kbase0 = Kh + krow0 * DH + kc8 * 8;
  const bf16_t* kbase1 = Kh + krow1 * DH + kc8 * 8;
  const int vsb = tid >> 2, vjp = tid & 3;
  const int vrg = vsb & 7, vc8 = vsb >> 3;
  const int vd0 = vc8 * 8 + vjp * 2, vd1 = vd0 + 1;
  const bf16_t* vbase = Vh + vrg * 8 * DH + vd0;

  // invariant swizzled fragment offsets (elements): row c, chunk (quad|quad+4)
  const int sw = c & 7;
  const int e0 = c * 64 + (quad ^ sw) * 8;
  const int e1 = c * 64 + ((quad + 4) ^ sw) * 8;

  bf16x8 kr0, kr1;
  uint32_t vr[8];
  auto load_tile = [&](int eoff) {
    kr0 = *(const bf16x8*)(kbase0 + eoff);
    kr1 = *(const bf16x8*)(kbase1 + eoff);
    const bf16_t* vp = vbase + eoff;
#pragma unroll
    for (int i = 0; i < 8; ++i) vr[i] = *(const uint32_t*)(vp + i * DH);
  };
  auto store_tile = [&](int buf) {
    *(bf16x8*)&KS[buf][(krow0 * 8 + (kc8 ^ (krow0 & 7))) * 8] = kr0;
    *(bf16x8*)&KS[buf][(krow1 * 8 + (kc8 ^ (krow1 & 7))) * 8] = kr1;
    union { bf16x8 v; uint16_t u[8]; } colA, colB;
#pragma unroll
    for (int i = 0; i < 8; ++i) {
      colA.u[i] = (uint16_t)(vr[i] & 0xffffu);
      colB.u[i] = (uint16_t)(vr[i] >> 16);
    }
    *(bf16x8*)&VtS[buf][(vd0 * 8 + (vrg ^ (vd0 & 7))) * 8] = colA.v;
    *(bf16x8*)&VtS[buf][(vd1 * 8 + (vrg ^ (vd1 & 7))) * 8] = colB.v;
  };

  // phase state (A first)
  int qtbase = qtA * 64;
  bf16x8 qf0 = *(const bf16x8*)(Qh + (qtbase + wave * 16 + c) * DH + quad * 8);
  bf16x8 qf1 = *(const bf16x8*)(Qh + (qtbase + wave * 16 + c) * DH + 32 + quad * 8);

  f32x4 o_acc[4] = {zero4, zero4, zero4, zero4};
  float m_r[4] = {-1e30f, -1e30f, -1e30f, -1e30f};
  float l_r[4] = {0.f, 0.f, 0.f, 0.f};

  auto write_O = [&](int qtb) {
#pragma unroll
    for (int r = 0; r < 4; ++r) {
      const int qg = qtb + wave * 16 + quad * 4 + r;
      const float inv = 1.0f / l_r[r];
#pragma unroll
      for (int ni = 0; ni < 4; ++ni)
        O[(b * TT + qg) * CC + h * 64 + ni * 16 + c] =
            (bf16_t)(o_acc[ni][r] * inv);
    }
  };

  load_tile(0);
  store_tile(0);
  __syncthreads();
  int coff = 0;   // current tile element offset into K/V
  int kkey = 0;   // current tile key-index base

// one kv iteration; CUR is a literal 0/1 -> LDS addresses fold to constants
#define ATTN_ITER(FI, CUR)                                                     \
  {                                                                            \
    const int fi_ = (FI);                                                      \
    const bool pre_ = fi_ < 32;                                                \
    const int noff_ = (fi_ + 1 == nA) ? 0 : coff + 64 * DH;                    \
    if (pre_) load_tile(noff_);                                                \
    bf16x8 kf0[4], kf1[4];                                                     \
    _Pragma("unroll") for (int ni = 0; ni < 4; ++ni) {                         \
      kf0[ni] = *(const bf16x8*)&KS[CUR][ni * 1024 + e0];                      \
      kf1[ni] = *(const bf16x8*)&KS[CUR][ni * 1024 + e1];                      \
    }                                                                          \
    f32x4 s[4];                                                                \
    _Pragma("unroll") for (int ni = 0; ni < 4; ++ni) {                         \
      f32x4 t = MFMA16(qf0, kf0[ni], zero4);                                   \
      t = MFMA16(qf1, kf1[ni], t);                                             \
      s[ni] = t;                                                               \
    }                                                                          \
    const int minq_ = qtbase + wave * 16;                                      \
    if (kkey + 63 > minq_) {                                                   \
      _Pragma("unroll") for (int ni = 0; ni < 4; ++ni)                         \
          _Pragma("unroll") for (int r = 0; r < 4; ++r) {                      \
        const int key_ = kkey + ni * 16 + c;                                   \
        const int qg_ = minq_ + quad * 4 + r;                                  \
        if (key_ > qg_) s[ni][r] = -1e30f;                                     \
      }                                                                        \
    }                                                                          \
    float alpha[4];                                                            \
    _Pragma("unroll") for (int r = 0; r < 4; ++r) {                            \
      float mx = fmaxf(fmaxf(s[0][r], s[1][r]), fmaxf(s[2][r], s[3][r]));      \
      mx = fmaxf(mx, __shfl_xor(mx, 1, 64));                                   \
      mx = fmaxf(mx, __shfl_xor(mx, 2, 64));                                   \
      mx = fmaxf(mx, __shfl_xor(mx, 4, 64));                                   \
      mx = fmaxf(mx, __shfl_xor(mx, 8, 64));                                   \
      const float mnew = fmaxf(m_r[r], mx);                                    \
      alpha[r] = __builtin_amdgcn_exp2f(m_r[r] - mnew);                        \
      m_r[r] = mnew;                                                           \
    }                                                                          \
    _Pragma("unroll") for (int ni = 0; ni < 4; ++ni)                           \
        _Pragma("unroll") for (int r = 0; r < 4; ++r) {                        \
      const float p = __builtin_amdgcn_exp2f(s[ni][r] - m_r[r]);               \
      const int prow_ = quad * 4 + r, pcol_ = ni * 16 + c;                     \
      PS[wave][(prow_ * 8 + ((pcol_ >> 3) ^ (prow_ & 7))) * 8 + (pcol_ & 7)] = \
          (bf16_t)p;                                                           \
    }                                                                          \
    _Pragma("unroll") for (int r = 0; r < 4; ++r) {                            \
      _Pragma("unroll") for (int ni = 0; ni < 4; ++ni)                         \
          o_acc[ni][r] *= alpha[r];                                            \
    }                                                                          \
    asm volatile("s_waitcnt lgkmcnt(0)" ::: "memory");                         \
    const bf16x8 p0 = *(const bf16x8*)&PS[wave][e0];                           \
    const bf16x8 p1 = *(const bf16x8*)&PS[wave][e1];                           \
    f32x4 rs = MFMA16(p0, ones8, zero4);                                       \
    rs = MFMA16(p1, ones8, rs);                                                \
    _Pragma("unroll") for (int ni = 0; ni < 4; ++ni) {                         \
      const bf16x8 v0 = *(const bf16x8*)&VtS[CUR][ni * 1024 + e0];             \
      const bf16x8 v1 = *(const bf16x8*)&VtS[CUR][ni * 1024 + e1];             \
      o_acc[ni] = MFMA16(p0, v0, o_acc[ni]);                                   \
      o_acc[ni] = MFMA16(p1, v1, o_acc[ni]);                                   \
    }                                                                          \
    _Pragma("unroll") for (int r = 0; r < 4; ++r)                              \
        l_r[r] = l_r[r] * alpha[r] + rs[r];                                    \
    if (fi_ == nA - 1) {                                                       \
      write_O(qtbase);                                                         \
      qtbase = qtB * 64;                                                       \
      qf0 = *(const bf16x8*)(Qh + (qtbase + wave * 16 + c) * DH + quad * 8);   \
      qf1 = *(const bf16x8*)(Qh + (qtbase + wave * 16 + c) * DH + 32 +         \
                             quad * 8);                                        \
      _Pragma("unroll") for (int r = 0; r < 4; ++r) {                          \
        m_r[r] = -1e30f;                                                       \
        l_r[r] = 0.f;                                                          \
      }                                                                        \
      _Pragma("unroll") for (int ni = 0; ni < 4; ++ni) o_acc[ni] = zero4;      \
    }                                                                          \
    if (pre_) store_tile(1 - (CUR));                                           \
    __syncthreads();                                                           \
    coff = noff_;                                                              \
    kkey = (fi_ + 1 == nA) ? 0 : kkey + 64;                                    \
  }

  for (int fj = 0; fj < 16; ++fj) {
    ATTN_ITER(2 * fj, 0)
    ATTN_ITER(2 * fj + 1, 1)
  }
  ATTN_ITER(32, 0)
#undef ATTN_ITER

  write_O(qtbase);  // phase B epilogue
}

// ---------------------------------------------------------------------------
extern "C" void kernel_launch(void* const* d_in, const int* in_sizes, int n_in,
                              void* d_out, int out_size, void* d_ws,
                              size_t ws_size, hipStream_t stream) {
  // Resolve inputs by unique element-count signature.
  const float *x = nullptr, *fcos = nullptr, *fsin = nullptr;
  const float *qkv_w = nullptr, *qkv_b = nullptr, *proj_w = nullptr, *proj_b = nullptr;
  for (int i = 0; i < n_in; ++i) {
    const int s = in_sizes[i];
    const float* p = (const float*)d_in[i];
    if (s == BB * TT * CC) x = p;                        // 8388608
    else if (s == TT * (DH / 2)) { if (!fcos) fcos = p; else fsin = p; }
    else if (s == NQKV * CC) qkv_w = p;                  // 3145728
    else if (s == NQKV) qkv_b = p;                       // 3072
    else if (s == CC * CC) proj_w = p;                   // 1048576
    else if (s == CC) proj_b = p;                        // 1024
    // mask (TT*TT) unused; causality is structural
  }

  const size_t NE = (size_t)BB * TT * CC;  // 8388608
  bf16_t* Qb = (bf16_t*)d_ws;
  bf16_t* Kb = Qb + NE;
  bf16_t* Vb = Kb + NE;
  bf16_t* Ob = Vb + NE;
  // dead-region reuse (all hazard-free under stream ordering):
  bf16_t* xb = Ob;                 // x_bf16 lives in Ob region until attn
  bf16_t* wqkvb = (bf16_t*)d_out;  // qkv_w bf16 in d_out until gemm3 writes it
  bf16_t* wpb = Qb;                // proj_w bf16 in Qb region (dead after attn)

  // converts
  cvt_k<<<dim3((int)(NE / 2048)), 256, 0, stream>>>(x, xb, (int)NE);
  cvt_k<<<dim3(NQKV * CC / 2048), 256, 0, stream>>>(qkv_w, wqkvb, NQKV * CC);

  // 1) qkv = x @ qkv_w^T + b, fused RoPE + head-split (+0.125*log2e into Q)
  gemm_k<0, 4><<<dim3(NQKV / 256, (BB * TT) / 256), 512, 0, stream>>>(
      xb, wqkvb, qkv_b, fcos, fsin, (void*)Qb, Kb, Vb);
  // 2) causal flash attention -> Ob (B*T, C) bf16 (overwrites xb)
  attn_k<<<dim3(BB * HH * 16), 256, 0, stream>>>(Qb, Kb, Vb, Ob);
  // 3) convert proj_w (Qb dead now), then out = Ob @ proj_w^T + proj_b (fp32)
  // BN=128 -> grid 8x32 = 256 blocks = exactly one balanced round on 256 CUs.
  cvt_k<<<dim3(CC * CC / 2048), 256, 0, stream>>>(proj_w, wpb, CC * CC);
  gemm_k<1, 2><<<dim3(CC / 128, (BB * TT) / 256), 512, 0, stream>>>(
      Ob, wpb, proj_b, nullptr, nullptr, d_out, nullptr, nullptr);
}

// Round 3
// 306.989 us; speedup vs baseline: 1.1069x; 1.0914x over previous
//
#include <hip/hip_runtime.h>
#include <stdint.h>

// Problem constants
#define BB 4
#define TT 2048
#define CC 1024
#define HH 16
#define DH 64
#define NQKV 3072

typedef __bf16 bf16_t;
typedef __attribute__((ext_vector_type(8))) __bf16 bf16x8;
typedef __attribute__((ext_vector_type(4))) float f32x4;

#define MFMA16(a, b, c) __builtin_amdgcn_mfma_f32_16x16x32_bf16((a), (b), (c), 0, 0, 0)

// async global->LDS, 16B per lane. LDS dest = wave-uniform base + lane*16.
__device__ __forceinline__ void gll16(const void* g, void* l) {
  typedef const __attribute__((address_space(1))) void* gp_t;
  typedef __attribute__((address_space(3))) void* lp_t;
  __builtin_amdgcn_global_load_lds((gp_t)(uintptr_t)g, (lp_t)(uintptr_t)l, 16, 0, 0);
}

// ---------------------------------------------------------------------------
// fp32 -> bf16 convert, 8 elems/thread (n multiple of 2048)
// ---------------------------------------------------------------------------
__global__ __launch_bounds__(256) void cvt_k(const float* __restrict__ src,
                                             bf16_t* __restrict__ dst, int n) {
  const int i8 = (blockIdx.x * 256 + threadIdx.x) * 8;
  if (i8 < n) {
    const f32x4 a = *(const f32x4*)(src + i8);
    const f32x4 b = *(const f32x4*)(src + i8 + 4);
    bf16x8 r;
    r[0] = (bf16_t)a[0]; r[1] = (bf16_t)a[1]; r[2] = (bf16_t)a[2]; r[3] = (bf16_t)a[3];
    r[4] = (bf16_t)b[0]; r[5] = (bf16_t)b[1]; r[6] = (bf16_t)b[2]; r[7] = (bf16_t)b[3];
    *(bf16x8*)(dst + i8) = r;
  }
}

// ---------------------------------------------------------------------------
// GEMM (bf16 A, bf16 W): C[m][n] = sum_k A[m][k]*W[n][k] (+bias[n]); K=1024.
// R2: back to the verified 128x128 / 256-thread / 32KB-LDS structure (R8/R0
// baseline, 110.9us), with two targeted changes:
//  (1) stage-ahead 2-phase pipeline: the old [2] half-index becomes a DOUBLE
//      BUFFER index (BK=32 per step, 32 steps). Per step: issue next step's
//      4 gll16 into buf^1 FIRST, then ds_read+16xMFMA on buf[cur], then a
//      single vmcnt(0)+s_barrier. Same LDS (32KB), same occupancy (~5
//      blocks/CU), same barrier count (32), same accumulation order — but the
//      drain now sits a full compute phase after issue instead of 0 instrs
//      after (the m97 ~20% drain stall). [catalog T3-minimum; m248v2 +10%]
//  (2) bijective XCD-chunked blockIdx swizzle (T1): each XCD gets a
//      contiguous run of logical ids (lx fastest) -> 8 M-rows x all N per
//      XCD; A-chunk (2MB) becomes L2-resident (4MB/XCD). FETCH was 85MB vs
//      23MB unique -> expect 55-75MB.
// LDS is XOR-swizzled exactly as baseline: logical (row r, chunk cc) at slot
// r*4 + (cc ^ (r&3)); gather permutes the per-lane global source (R9-verified).
// EPI==0: qkv epilogue (RoPE Q/K, 0.125*log2e folded into Q, scatter B,H,T,dh)
// EPI==1: bias epilogue into fp32 out0
// ---------------------------------------------------------------------------
template <int EPI>
__global__ __launch_bounds__(256) void gemm_k(
    const bf16_t* __restrict__ A, const bf16_t* __restrict__ W,
    const float* __restrict__ bias,
    const float* __restrict__ fcos, const float* __restrict__ fsin,
    void* __restrict__ out0v, bf16_t* __restrict__ out1,
    bf16_t* __restrict__ out2) {
  __shared__ bf16_t Alds[2][128 * 32];  // [dbuf][128 rows x 32 k]
  __shared__ bf16_t Blds[2][128 * 32];
  const int K = 1024;
  const int tid = threadIdx.x;
  const int lane = tid & 63, wave = tid >> 6;
  const int quad = lane >> 4, c = lane & 15;
  const int wm = wave >> 1, wn = wave & 1;

  // XCD-chunked bijective swizzle (nwg divisible by 8 in both gemms).
  const int nwgx = gridDim.x;
  const int d = blockIdx.y * nwgx + blockIdx.x;  // dispatch order (x fastest)
  const int cpx = (nwgx * gridDim.y) >> 3;
  const int lg = (d & 7) * cpx + (d >> 3);
  const int bx = lg % nwgx, by = lg / nwgx;
  const int mbase = by * 128, nbase = bx * 128;

  f32x4 acc[4][4];
#pragma unroll
  for (int i = 0; i < 4; ++i)
#pragma unroll
    for (int j = 0; j < 4; ++j) acc[i][j] = (f32x4){0.f, 0.f, 0.f, 0.f};

  // permuted gather: slot s=tid (+256) holds logical (r=s>>2, cc=(s&3)^(r&3))
  const int s0 = tid, s1 = tid + 256;
  const int r0 = s0 >> 2, cc0 = (s0 & 3) ^ (r0 & 3);
  const int r1 = s1 >> 2, cc1 = (s1 & 3) ^ (r1 & 3);
  const bf16_t* ag0 = A + (mbase + r0) * K + cc0 * 8;
  const bf16_t* ag1 = A + (mbase + r1) * K + cc1 * 8;
  const bf16_t* bg0 = W + (nbase + r0) * K + cc0 * 8;
  const bf16_t* bg1 = W + (nbase + r1) * K + cc1 * 8;

#define GSTAGE(BUF, KO)                        \
  {                                            \
    gll16(ag0 + (KO), &Alds[BUF][s0 * 8]);     \
    gll16(ag1 + (KO), &Alds[BUF][s1 * 8]);     \
    gll16(bg0 + (KO), &Blds[BUF][s0 * 8]);     \
    gll16(bg1 + (KO), &Blds[BUF][s1 * 8]);     \
  }

// One BK=32 step. CUR is a literal 0/1; STG gates stage+barrier (off on the
// final step). Stage for step KS+1 goes into buf CUR^1 (its readers finished
// before the previous step's barrier).
#define GSTEP(KS, CUR, STG)                                                    \
  {                                                                            \
    if (STG) GSTAGE((CUR) ^ 1, ((KS) + 1) * 32);                               \
    bf16x8 af[4], bfr[4];                                                      \
    _Pragma("unroll") for (int mi = 0; mi < 4; ++mi) {                         \
      const int row = wm * 64 + mi * 16 + c;                                   \
      af[mi] = *(const bf16x8*)&Alds[CUR][(row * 4 + (quad ^ (row & 3))) * 8]; \
    }                                                                          \
    _Pragma("unroll") for (int ni = 0; ni < 4; ++ni) {                         \
      const int row = wn * 64 + ni * 16 + c;                                   \
      bfr[ni] =                                                                \
          *(const bf16x8*)&Blds[CUR][(row * 4 + (quad ^ (row & 3))) * 8];      \
    }                                                                          \
    _Pragma("unroll") for (int mi = 0; mi < 4; ++mi)                           \
        _Pragma("unroll") for (int ni = 0; ni < 4; ++ni)                       \
            acc[mi][ni] = MFMA16(af[mi], bfr[ni], acc[mi][ni]);                \
    if (STG) {                                                                 \
      asm volatile("s_waitcnt vmcnt(0)" ::: "memory");                         \
      __builtin_amdgcn_s_barrier();                                            \
      asm volatile("" ::: "memory");                                           \
    }                                                                          \
  }

  // prologue: stage step 0, drain, barrier
  GSTAGE(0, 0);
  asm volatile("s_waitcnt vmcnt(0)" ::: "memory");
  __builtin_amdgcn_s_barrier();
  asm volatile("" ::: "memory");

  // steps 0..29 (15 unrolled pairs), then 30 (stages 31), then 31 (no stage)
  for (int fj = 0; fj < 15; ++fj) {
    GSTEP(2 * fj, 0, 1)
    GSTEP(2 * fj + 1, 1, 1)
  }
  GSTEP(30, 0, 1)
  GSTEP(31, 1, 0)
#undef GSTEP
#undef GSTAGE

  // epilogue. C/D layout: col = lane&15 (+16*ni), row = quad*4 + r (+16*mi)
  const float qscale = 0.18033688011112042f;  // 0.125 * log2(e)
#pragma unroll
  for (int mi = 0; mi < 4; ++mi) {
#pragma unroll
    for (int ni = 0; ni < 4; ++ni) {
      const int n = nbase + wn * 64 + ni * 16 + c;
      const float bv = bias[n];
#pragma unroll
      for (int r = 0; r < 4; ++r) {
        const int m = mbase + wm * 64 + mi * 16 + quad * 4 + r;
        float v = acc[mi][ni][r] + bv;
        if (EPI == 0) {
          bf16_t* out0 = (bf16_t*)out0v;
          const int sel = n >> 10;  // 0=q 1=k 2=v
          const int nl = n & 1023;
          const int h = nl >> 6, dd = nl & 63;
          const int b = m >> 11, t = m & 2047;
          const int dst = ((b * HH + h) * TT + t) * DH + dd;
          if (sel < 2) {
            const float pv = __shfl_xor(v, 1, 64);  // RoPE partner (col n^1)
            const int d2 = dd >> 1;
            const float cs = fcos[t * 32 + d2];
            const float sn = fsin[t * 32 + d2];
            float o = ((dd & 1) == 0) ? (v * cs - pv * sn) : (pv * sn + v * cs);
            if (sel == 0) {
              o *= qscale;
              out0[dst] = (bf16_t)o;
            } else {
              out1[dst] = (bf16_t)o;
            }
          } else {
            out2[dst] = (bf16_t)v;
          }
        } else {
          float* outf = (float*)out0v;
          outf[m * CC + n] = v;
        }
      }
    }
  }
}

// ---------------------------------------------------------------------------
// Flash attention, causal. Q pre-scaled by 0.125*log2(e) (exp2 domain).
// R8-verified version (REVERT of R9's global-K experiment: MFMA operands must
// come from a buffer filled >=1 iteration ahead; direct global K reads put
// ~200-900cyc load latency on the critical path -> 105->174us regression).
// Uniform-work causal pairing: exactly 33 kv-iterations per block; kv-loop
// unrolled x2 (compile-time LDS buffer index); rowsum via MFMA vs ones;
// XOR-swizzled LDS (0 bank conflicts).
// ---------------------------------------------------------------------------
__global__ __launch_bounds__(256, 4) void attn_k(const bf16_t* __restrict__ Q,
                                                 const bf16_t* __restrict__ Kv,
                                                 const bf16_t* __restrict__ V,
                                                 bf16_t* __restrict__ O) {
  __shared__ bf16_t KS[2][64 * 64];
  __shared__ bf16_t VtS[2][64 * 64];
  __shared__ bf16_t PS[4][16 * 64];

  const int tid = threadIdx.x;
  const int lane = tid & 63, wave = tid >> 6;
  const int quad = lane >> 4, c = lane & 15;
  const int bi = blockIdx.x;
  const int pair = bi & 15, h = (bi >> 4) & 15, b = bi >> 8;
  const int qtA = pair, qtB = 31 - pair;
  const int nA = qtA + 1;  // kv tiles in phase A

  const bf16_t* Qh = Q + ((b * HH + h) * TT) * DH;
  const bf16_t* Kh = Kv + ((b * HH + h) * TT) * DH;
  const bf16_t* Vh = V + ((b * HH + h) * TT) * DH;

  const f32x4 zero4 = {0.f, 0.f, 0.f, 0.f};
  bf16x8 ones8;
#pragma unroll
  for (int i = 0; i < 8; ++i) ones8[i] = (bf16_t)1.0f;

  // staging bases (per-thread, loop-invariant)
  const int krow0 = tid >> 3, kc8 = tid & 7, krow1 = krow0 + 32;
  const bf16_t* kbase0 = Kh + krow0 * DH + kc8 * 8;
  const bf16_t* kbase1 = Kh + krow1 * DH + kc8 * 8;
  const int vsb = tid >> 2, vjp = tid & 3;
  const int vrg = vsb & 7, vc8 = vsb >> 3;
  const int vd0 = vc8 * 8 + vjp * 2, vd1 = vd0 + 1;
  const bf16_t* vbase = Vh + vrg * 8 * DH + vd0;

  // invariant swizzled fragment offsets (elements): row c, chunk (quad|quad+4)
  const int sw = c & 7;
  const int e0 = c * 64 + (quad ^ sw) * 8;
  const int e1 = c * 64 + ((quad + 4) ^ sw) * 8;

  bf16x8 kr0, kr1;
  uint32_t vr[8];
  auto load_tile = [&](int eoff) {
    kr0 = *(const bf16x8*)(kbase0 + eoff);
    kr1 = *(const bf16x8*)(kbase1 + eoff);
    const bf16_t* vp = vbase + eoff;
#pragma unroll
    for (int i = 0; i < 8; ++i) vr[i] = *(const uint32_t*)(vp + i * DH);
  };
  auto store_tile = [&](int buf) {
    *(bf16x8*)&KS[buf][(krow0 * 8 + (kc8 ^ (krow0 & 7))) * 8] = kr0;
    *(bf16x8*)&KS[buf][(krow1 * 8 + (kc8 ^ (krow1 & 7))) * 8] = kr1;
    union { bf16x8 v; uint16_t u[8]; } colA, colB;
#pragma unroll
    for (int i = 0; i < 8; ++i) {
      colA.u[i] = (uint16_t)(vr[i] & 0xffffu);
      colB.u[i] = (uint16_t)(vr[i] >> 16);
    }
    *(bf16x8*)&VtS[buf][(vd0 * 8 + (vrg ^ (vd0 & 7))) * 8] = colA.v;
    *(bf16x8*)&VtS[buf][(vd1 * 8 + (vrg ^ (vd1 & 7))) * 8] = colB.v;
  };

  // phase state (A first)
  int qtbase = qtA * 64;
  bf16x8 qf0 = *(const bf16x8*)(Qh + (qtbase + wave * 16 + c) * DH + quad * 8);
  bf16x8 qf1 = *(const bf16x8*)(Qh + (qtbase + wave * 16 + c) * DH + 32 + quad * 8);

  f32x4 o_acc[4] = {zero4, zero4, zero4, zero4};
  float m_r[4] = {-1e30f, -1e30f, -1e30f, -1e30f};
  float l_r[4] = {0.f, 0.f, 0.f, 0.f};

  auto write_O = [&](int qtb) {
#pragma unroll
    for (int r = 0; r < 4; ++r) {
      const int qg = qtb + wave * 16 + quad * 4 + r;
      const float inv = 1.0f / l_r[r];
#pragma unroll
      for (int ni = 0; ni < 4; ++ni)
        O[(b * TT + qg) * CC + h * 64 + ni * 16 + c] =
            (bf16_t)(o_acc[ni][r] * inv);
    }
  };

  load_tile(0);
  store_tile(0);
  __syncthreads();
  int coff = 0;   // current tile element offset into K/V
  int kkey = 0;   // current tile key-index base

// one kv iteration; CUR is a literal 0/1 -> LDS addresses fold to constants
#define ATTN_ITER(FI, CUR)                                                     \
  {                                                                            \
    const int fi_ = (FI);                                                      \
    const bool pre_ = fi_ < 32;                                                \
    const int noff_ = (fi_ + 1 == nA) ? 0 : coff + 64 * DH;                    \
    if (pre_) load_tile(noff_);                                                \
    bf16x8 kf0[4], kf1[4];                                                     \
    _Pragma("unroll") for (int ni = 0; ni < 4; ++ni) {                         \
      kf0[ni] = *(const bf16x8*)&KS[CUR][ni * 1024 + e0];                      \
      kf1[ni] = *(const bf16x8*)&KS[CUR][ni * 1024 + e1];                      \
    }                                                                          \
    f32x4 s[4];                                                                \
    _Pragma("unroll") for (int ni = 0; ni < 4; ++ni) {                         \
      f32x4 t = MFMA16(qf0, kf0[ni], zero4);                                   \
      t = MFMA16(qf1, kf1[ni], t);                                             \
      s[ni] = t;                                                               \
    }                                                                          \
    const int minq_ = qtbase + wave * 16;                                      \
    if (kkey + 63 > minq_) {                                                   \
      _Pragma("unroll") for (int ni = 0; ni < 4; ++ni)                         \
          _Pragma("unroll") for (int r = 0; r < 4; ++r) {                      \
        const int key_ = kkey + ni * 16 + c;                                   \
        const int qg_ = minq_ + quad * 4 + r;                                  \
        if (key_ > qg_) s[ni][r] = -1e30f;                                     \
      }                                                                        \
    }                                                                          \
    float alpha[4];                                                            \
    _Pragma("unroll") for (int r = 0; r < 4; ++r) {                            \
      float mx = fmaxf(fmaxf(s[0][r], s[1][r]), fmaxf(s[2][r], s[3][r]));      \
      mx = fmaxf(mx, __shfl_xor(mx, 1, 64));                                   \
      mx = fmaxf(mx, __shfl_xor(mx, 2, 64));                                   \
      mx = fmaxf(mx, __shfl_xor(mx, 4, 64));                                   \
      mx = fmaxf(mx, __shfl_xor(mx, 8, 64));                                   \
      const float mnew = fmaxf(m_r[r], mx);                                    \
      alpha[r] = __builtin_amdgcn_exp2f(m_r[r] - mnew);                        \
      m_r[r] = mnew;                                                           \
    }                                                                          \
    _Pragma("unroll") for (int ni = 0; ni < 4; ++ni)                           \
        _Pragma("unroll") for (int r = 0; r < 4; ++r) {                        \
      const float p = __builtin_amdgcn_exp2f(s[ni][r] - m_r[r]);               \
      const int prow_ = quad * 4 + r, pcol_ = ni * 16 + c;                     \
      PS[wave][(prow_ * 8 + ((pcol_ >> 3) ^ (prow_ & 7))) * 8 + (pcol_ & 7)] = \
          (bf16_t)p;                                                           \
    }                                                                          \
    _Pragma("unroll") for (int r = 0; r < 4; ++r) {                            \
      _Pragma("unroll") for (int ni = 0; ni < 4; ++ni)                         \
          o_acc[ni][r] *= alpha[r];                                            \
    }                                                                          \
    asm volatile("s_waitcnt lgkmcnt(0)" ::: "memory");                         \
    const bf16x8 p0 = *(const bf16x8*)&PS[wave][e0];                           \
    const bf16x8 p1 = *(const bf16x8*)&PS[wave][e1];                           \
    f32x4 rs = MFMA16(p0, ones8, zero4);                                       \
    rs = MFMA16(p1, ones8, rs);                                                \
    _Pragma("unroll") for (int ni = 0; ni < 4; ++ni) {                         \
      const bf16x8 v0 = *(const bf16x8*)&VtS[CUR][ni * 1024 + e0];             \
      const bf16x8 v1 = *(const bf16x8*)&VtS[CUR][ni * 1024 + e1];             \
      o_acc[ni] = MFMA16(p0, v0, o_acc[ni]);                                   \
      o_acc[ni] = MFMA16(p1, v1, o_acc[ni]);                                   \
    }                                                                          \
    _Pragma("unroll") for (int r = 0; r < 4; ++r)                              \
        l_r[r] = l_r[r] * alpha[r] + rs[r];                                    \
    if (fi_ == nA - 1) {                                                       \
      write_O(qtbase);                                                         \
      qtbase = qtB * 64;                                                       \
      qf0 = *(const bf16x8*)(Qh + (qtbase + wave * 16 + c) * DH + quad * 8);   \
      qf1 = *(const bf16x8*)(Qh + (qtbase + wave * 16 + c) * DH + 32 +         \
                             quad * 8);                                        \
      _Pragma("unroll") for (int r = 0; r < 4; ++r) {                          \
        m_r[r] = -1e30f;                                                       \
        l_r[r] = 0.f;                                                          \
      }                                                                        \
      _Pragma("unroll") for (int ni = 0; ni < 4; ++ni) o_acc[ni] = zero4;      \
    }                                                                          \
    if (pre_) store_tile(1 - (CUR));                                           \
    __syncthreads();                                                           \
    coff = noff_;                                                              \
    kkey = (fi_ + 1 == nA) ? 0 : kkey + 64;                                    \
  }

  for (int fj = 0; fj < 16; ++fj) {
    ATTN_ITER(2 * fj, 0)
    ATTN_ITER(2 * fj + 1, 1)
  }
  ATTN_ITER(32, 0)
#undef ATTN_ITER

  write_O(qtbase);  // phase B epilogue
}

// ---------------------------------------------------------------------------
extern "C" void kernel_launch(void* const* d_in, const int* in_sizes, int n_in,
                              void* d_out, int out_size, void* d_ws,
                              size_t ws_size, hipStream_t stream) {
  // Resolve inputs by unique element-count signature.
  const float *x = nullptr, *fcos = nullptr, *fsin = nullptr;
  const float *qkv_w = nullptr, *qkv_b = nullptr, *proj_w = nullptr, *proj_b = nullptr;
  for (int i = 0; i < n_in; ++i) {
    const int s = in_sizes[i];
    const float* p = (const float*)d_in[i];
    if (s == BB * TT * CC) x = p;                        // 8388608
    else if (s == TT * (DH / 2)) { if (!fcos) fcos = p; else fsin = p; }
    else if (s == NQKV * CC) qkv_w = p;                  // 3145728
    else if (s == NQKV) qkv_b = p;                       // 3072
    else if (s == CC * CC) proj_w = p;                   // 1048576
    else if (s == CC) proj_b = p;                        // 1024
    // mask (TT*TT) unused; causality is structural
  }

  const size_t NE = (size_t)BB * TT * CC;  // 8388608
  bf16_t* Qb = (bf16_t*)d_ws;
  bf16_t* Kb = Qb + NE;
  bf16_t* Vb = Kb + NE;
  bf16_t* Ob = Vb + NE;
  // dead-region reuse (all hazard-free under stream ordering):
  bf16_t* xb = Ob;                 // x_bf16 lives in Ob region until attn
  bf16_t* wqkvb = (bf16_t*)d_out;  // qkv_w bf16 in d_out until gemm3 writes it
  bf16_t* wpb = Qb;                // proj_w bf16 in Qb region (dead after attn)

  // converts
  cvt_k<<<dim3((int)(NE / 2048)), 256, 0, stream>>>(x, xb, (int)NE);
  cvt_k<<<dim3(NQKV * CC / 2048), 256, 0, stream>>>(qkv_w, wqkvb, NQKV * CC);

  // 1) qkv = x @ qkv_w^T + b, fused RoPE + head-split (+0.125*log2e into Q)
  gemm_k<0><<<dim3(NQKV / 128, (BB * TT) / 128), 256, 0, stream>>>(
      xb, wqkvb, qkv_b, fcos, fsin, (void*)Qb, Kb, Vb);
  // 2) causal flash attention -> Ob (B*T, C) bf16 (overwrites xb)
  attn_k<<<dim3(BB * HH * 16), 256, 0, stream>>>(Qb, Kb, Vb, Ob);
  // 3) convert proj_w (Qb dead now), then out = Ob @ proj_w^T + proj_b (fp32)
  cvt_k<<<dim3(CC * CC / 2048), 256, 0, stream>>>(proj_w, wpb, CC * CC);
  gemm_k<1><<<dim3(CC / 128, (BB * TT) / 128), 256, 0, stream>>>(
      Ob, wpb, proj_b, nullptr, nullptr, d_out, nullptr, nullptr);
}